// Round 6
// baseline (129.247 us; speedup 1.0000x reference)
//
#include <hip/hip_runtime.h>
#include <stdint.h>
#include <stddef.h>

#define BATCH 65536
#define OUTF  1024
#define INF   128

typedef float f32x4 __attribute__((ext_vector_type(4)));
typedef __bf16 bf16x8 __attribute__((ext_vector_type(8)));

// RNE float->bf16, packed pair: lo halfword = a, hi halfword = b
__device__ inline uint32_t pack_bf16_rne(float a, float b) {
    uint32_t ua = __builtin_bit_cast(uint32_t, a);
    uint32_t ub = __builtin_bit_cast(uint32_t, b);
    ua += 0x7fffu + ((ua >> 16) & 1u);
    ub += 0x7fffu + ((ub >> 16) & 1u);
    return (ua >> 16) | (ub & 0xffff0000u);
}

// Prep: one wave per row. Reads fp32 row (128 elems), writes bf16 row
// (64 u32, coalesced 256B) and the row sum-of-squares.
// rows [0, BATCH) -> x, rows [BATCH, BATCH+OUTF) -> w.
__global__ __launch_bounds__(256) void prep_kernel(
        const float* __restrict__ x, const float* __restrict__ w,
        float* __restrict__ sumsq, uint32_t* __restrict__ xb,
        uint32_t* __restrict__ wb) {
    int gtid = blockIdx.x * 256 + threadIdx.x;
    int row  = gtid >> 6;
    int lane = threadIdx.x & 63;
    if (row >= BATCH + OUTF) return;
    const float* src;
    uint32_t* dst;
    if (row < BATCH) {
        src = x + (size_t)row * INF;
        dst = xb + (size_t)row * 64;
    } else {
        src = w + (size_t)(row - BATCH) * INF;
        dst = wb + (size_t)(row - BATCH) * 64;
    }
    float2 v = *(const float2*)(src + lane * 2);
    dst[lane] = pack_bf16_rne(v.x, v.y);
    float s = v.x * v.x + v.y * v.y;
    #pragma unroll
    for (int off = 32; off; off >>= 1) s += __shfl_down(s, off);
    if (lane == 0) sumsq[row] = s;
}

// Barrier-free GEMM: 512 blocks x 256 threads. Each wave owns 32 x-rows and
// sweeps all 1024 cols in 16 chunks of 64. A-frags live in registers for the
// whole kernel; B-frags stream from L2-resident W; epilogue stores directly
// from accumulators (nontemporal). No LDS, no __syncthreads -> stores
// pipeline continuously, never forced to drain at barriers.
__global__ __launch_bounds__(256, 2) void gemm_epi_kernel(
        const __bf16* __restrict__ xb, const __bf16* __restrict__ wb,
        const float* __restrict__ x2, const float* __restrict__ w2,
        float* __restrict__ out) {
    int tid  = threadIdx.x;
    int wid  = tid >> 6;
    int lane = tid & 63;
    int l16  = lane & 15;   // fragment row/col
    int lq   = lane >> 4;   // k-quarter / row-quad selector

    int row_base = blockIdx.x * 128 + wid * 32;   // this wave's 32 rows

    // A fragments: 2 im-groups x 4 ks, each 16B/lane. 32 VGPRs, loaded once.
    bf16x8 a[4][2];
    #pragma unroll
    for (int ks = 0; ks < 4; ++ks)
        #pragma unroll
        for (int im = 0; im < 2; ++im)
            a[ks][im] = *(const bf16x8*)(
                xb + (size_t)(row_base + im * 16 + l16) * INF + ks * 32 + lq * 8);

    // x2 for this lane's epilogue rows: rows im*16 + lq*4 + r, r=0..3
    f32x4 x2v[2];
    #pragma unroll
    for (int im = 0; im < 2; ++im)
        x2v[im] = *(const f32x4*)&x2[row_base + im * 16 + lq * 4];

    for (int nc = 0; nc < 16; ++nc) {
        int n0 = nc * 64;

        float w2v[4];
        #pragma unroll
        for (int in = 0; in < 4; ++in)
            w2v[in] = w2[n0 + in * 16 + l16];

        f32x4 acc[2][4];
        #pragma unroll
        for (int im = 0; im < 2; ++im)
            #pragma unroll
            for (int in = 0; in < 4; ++in)
                acc[im][in] = f32x4{0.f, 0.f, 0.f, 0.f};

        #pragma unroll
        for (int ks = 0; ks < 4; ++ks) {
            bf16x8 b[4];
            #pragma unroll
            for (int in = 0; in < 4; ++in)
                b[in] = *(const bf16x8*)(
                    wb + (size_t)(n0 + in * 16 + l16) * INF + ks * 32 + lq * 8);
            #pragma unroll
            for (int im = 0; im < 2; ++im)
                #pragma unroll
                for (int in = 0; in < 4; ++in)
                    acc[im][in] = __builtin_amdgcn_mfma_f32_16x16x32_bf16(
                        a[ks][im], b[in], acc[im][in], 0, 0, 0);
        }

        // Epilogue straight from acc. C/D layout: col = l16, row = lq*4 + r.
        #pragma unroll
        for (int im = 0; im < 2; ++im) {
            #pragma unroll
            for (int in = 0; in < 4; ++in) {
                #pragma unroll
                for (int r = 0; r < 4; ++r) {
                    int row = row_base + im * 16 + lq * 4 + r;
                    int col = n0 + in * 16 + l16;
                    float d2 = x2v[im][r] + w2v[in] - 2.0f * acc[im][in][r];
                    float o  = -0.5f * __builtin_amdgcn_sqrtf(fmaxf(d2, 0.0f));
                    __builtin_nontemporal_store(
                        o, &out[(size_t)row * OUTF + col]);
                }
            }
        }
    }
}

extern "C" void kernel_launch(void* const* d_in, const int* in_sizes, int n_in,
                              void* d_out, int out_size, void* d_ws, size_t ws_size,
                              hipStream_t stream) {
    const float* x = (const float*)d_in[0];
    const float* w = (const float*)d_in[1];
    float* out = (float*)d_out;

    // ws layout: [0, 66560*4) f32 sumsq (x2 then w2);
    // xb (bf16 x, 16 MiB) at byte 266240 (256-aligned); wb after it.
    char* ws = (char*)d_ws;
    float* sumsq = (float*)ws;
    float* x2 = sumsq;
    float* w2 = sumsq + BATCH;
    uint32_t* xb_u32 = (uint32_t*)(ws + 266240);
    uint32_t* wb_u32 = (uint32_t*)(ws + 266240 + (size_t)BATCH * INF * 2);
    const __bf16* xb = (const __bf16*)xb_u32;
    const __bf16* wb = (const __bf16*)wb_u32;

    prep_kernel<<<dim3((BATCH + OUTF) / 4), dim3(256), 0, stream>>>(
        x, w, sumsq, xb_u32, wb_u32);
    gemm_epi_kernel<<<dim3(512), dim3(256), 0, stream>>>(xb, wb, x2, w2, out);
}

// Round 7
// 112.085 us; speedup vs baseline: 1.1531x; 1.1531x over previous
//
#include <hip/hip_runtime.h>
#include <stdint.h>
#include <stddef.h>

#define BATCH 65536
#define OUTF  1024
#define INF   128

typedef float f32x4 __attribute__((ext_vector_type(4)));
typedef __bf16 bf16x8 __attribute__((ext_vector_type(8)));

// RNE float->bf16, packed pair: lo halfword = a, hi halfword = b
__device__ inline uint32_t pack_bf16_rne(float a, float b) {
    uint32_t ua = __builtin_bit_cast(uint32_t, a);
    uint32_t ub = __builtin_bit_cast(uint32_t, b);
    ua += 0x7fffu + ((ua >> 16) & 1u);
    ub += 0x7fffu + ((ub >> 16) & 1u);
    return (ua >> 16) | (ub & 0xffff0000u);
}

// Load 8 contiguous fp32, accumulate sum of squares, return bf16x8 fragment.
__device__ inline bf16x8 load_frag_x2(const float* __restrict__ p, float& s) {
    f32x4 v0 = *(const f32x4*)(p);
    f32x4 v1 = *(const f32x4*)(p + 4);
    s += v0.x * v0.x + v0.y * v0.y + v0.z * v0.z + v0.w * v0.w
       + v1.x * v1.x + v1.y * v1.y + v1.z * v1.z + v1.w * v1.w;
    union { uint32_t u[4]; bf16x8 b; } f;
    f.u[0] = pack_bf16_rne(v0.x, v0.y);
    f.u[1] = pack_bf16_rne(v0.z, v0.w);
    f.u[2] = pack_bf16_rne(v1.x, v1.y);
    f.u[3] = pack_bf16_rne(v1.z, v1.w);
    return f.b;
}

// W-only prep: one wave per w-row -> bf16 row + sumsq. 1024 rows, tiny.
__global__ __launch_bounds__(256) void wprep_kernel(
        const float* __restrict__ w, float* __restrict__ w2,
        uint32_t* __restrict__ wb) {
    int gtid = blockIdx.x * 256 + threadIdx.x;
    int row  = gtid >> 6;
    int lane = threadIdx.x & 63;
    if (row >= OUTF) return;
    const float* src = w + (size_t)row * INF;
    float2 v = *(const float2*)(src + lane * 2);
    wb[(size_t)row * 64 + lane] = pack_bf16_rne(v.x, v.y);
    float s = v.x * v.x + v.y * v.y;
    #pragma unroll
    for (int off = 32; off; off >>= 1) s += __shfl_down(s, off);
    if (lane == 0) w2[row] = s;
}

#define TPAD 132  // LDS row stride (floats)

// 128x128 tile per block, 4 waves (2x2), mfma 16x16x32 bf16.
// x is converted fp32->bf16 in-kernel (8 sibling blocks share the x panel via
// L2, nt-fast swizzle); x2 computed from the same loads via shfl reduction.
// Epilogue identical to R4: LDS transpose -> contiguous 512B/row NT float4.
__global__ __launch_bounds__(256, 2) void gemm_epi_kernel(
        const float* __restrict__ x, const __bf16* __restrict__ wb,
        const float* __restrict__ w2, float* __restrict__ out) {
    // bijective XCD-chunked swizzle: nwg = 4096 (divisible by 8), nt fastest.
    int bid = blockIdx.x;
    int swz = (bid & 7) * (4096 / 8) + (bid >> 3);
    int mt = swz >> 3;          // 512 m-tiles
    int nt = swz & 7;           // 8 n-tiles
    int m0 = mt * 128, n0 = nt * 128;

    int tid  = threadIdx.x;
    int wid  = tid >> 6;
    int lane = tid & 63;
    int wr = wid >> 1, wc = wid & 1;    // 2x2 wave grid, 64x64 per wave
    int row_base = m0 + wr * 64;
    int col_base = n0 + wc * 64;

    __shared__ float sw2[128];
    __shared__ float tile[128 * TPAD];
    if (tid < 128) sw2[tid] = w2[n0 + tid];
    __syncthreads();

    int l16 = lane & 15;   // fragment row/col
    int lq  = lane >> 4;   // k-quarter (main loop) / row-quad (epilogue)

    f32x4 acc[4][4];
    #pragma unroll
    for (int i = 0; i < 4; ++i)
        #pragma unroll
        for (int j = 0; j < 4; ++j)
            acc[i][j] = f32x4{0.f, 0.f, 0.f, 0.f};

    float x2p[4] = {0.f, 0.f, 0.f, 0.f};   // per-lane partial sumsq, row (im,l16)

    #pragma unroll
    for (int ks = 0; ks < 4; ++ks) {
        int kbase = ks * 32 + lq * 8;
        bf16x8 a[4], b[4];
        #pragma unroll
        for (int im = 0; im < 4; ++im)
            a[im] = load_frag_x2(
                &x[(size_t)(row_base + im * 16 + l16) * INF + kbase], x2p[im]);
        #pragma unroll
        for (int in = 0; in < 4; ++in)
            b[in] = *(const bf16x8*)(wb + (size_t)(col_base + in * 16 + l16) * INF + kbase);
        #pragma unroll
        for (int im = 0; im < 4; ++im)
            #pragma unroll
            for (int in = 0; in < 4; ++in)
                acc[im][in] = __builtin_amdgcn_mfma_f32_16x16x32_bf16(
                    a[im], b[in], acc[im][in], 0, 0, 0);
    }

    // Row sumsq: butterfly over the 4 k-quarter lane groups (xor 16, 32).
    // After this, every lane holds the full x2 of row (im, its l16).
    #pragma unroll
    for (int im = 0; im < 4; ++im) {
        float s = x2p[im];
        s += __shfl_xor(s, 16);
        s += __shfl_xor(s, 32);
        x2p[im] = s;
    }
    // Redistribute to epilogue layout: lane (lq,l16) needs x2 of row lq*4+r,
    // held by the lane with l16 == lq*4+r (same lq group): src = lq*20 + r.
    float x2row[4][4];
    #pragma unroll
    for (int im = 0; im < 4; ++im)
        #pragma unroll
        for (int r = 0; r < 4; ++r)
            x2row[im][r] = __shfl(x2p[im], lq * 20 + r);

    // Phase 1: fused epilogue math into LDS tile.
    // C/D layout (verified m89/m91): col = lane&15, row = (lane>>4)*4 + reg
    #pragma unroll
    for (int im = 0; im < 4; ++im) {
        #pragma unroll
        for (int in = 0; in < 4; ++in) {
            #pragma unroll
            for (int r = 0; r < 4; ++r) {
                int row = wr * 64 + im * 16 + lq * 4 + r;  // within 128-tile
                int col = wc * 64 + in * 16 + l16;
                float d2 = x2row[im][r] + sw2[col] - 2.0f * acc[im][in][r];
                tile[row * TPAD + col] = -0.5f * __builtin_amdgcn_sqrtf(fmaxf(d2, 0.0f));
            }
        }
    }
    __syncthreads();

    // Phase 2: coalesced nontemporal float4 stores, 512B contiguous per row.
    int cg = tid & 31;           // col group (16B)
    int r8 = tid >> 5;           // 0..7
    #pragma unroll
    for (int chunk = 0; chunk < 16; ++chunk) {
        int row = chunk * 8 + r8;
        f32x4 v = *(const f32x4*)&tile[row * TPAD + cg * 4];
        __builtin_nontemporal_store(
            v, (f32x4*)&out[(size_t)(m0 + row) * OUTF + n0 + cg * 4]);
    }
}

extern "C" void kernel_launch(void* const* d_in, const int* in_sizes, int n_in,
                              void* d_out, int out_size, void* d_ws, size_t ws_size,
                              hipStream_t stream) {
    const float* x = (const float*)d_in[0];
    const float* w = (const float*)d_in[1];
    float* out = (float*)d_out;

    // ws layout: w2 [1024 f32] at 0; wb (bf16 W, 256KB) at byte 4096.
    char* ws = (char*)d_ws;
    float* w2 = (float*)ws;
    uint32_t* wb_u32 = (uint32_t*)(ws + 4096);
    const __bf16* wb = (const __bf16*)wb_u32;

    wprep_kernel<<<dim3(OUTF / 4), dim3(256), 0, stream>>>(w, w2, wb_u32);
    gemm_epi_kernel<<<dim3(4096), dim3(256), 0, stream>>>(x, wb, w2, out);
}

// Round 8
// 99.410 us; speedup vs baseline: 1.3001x; 1.1275x over previous
//
#include <hip/hip_runtime.h>
#include <stdint.h>
#include <stddef.h>

#define BATCH 65536
#define OUTF  1024
#define INF   128

typedef float f32x4 __attribute__((ext_vector_type(4)));
typedef __bf16 bf16x8 __attribute__((ext_vector_type(8)));

// RNE float->bf16, packed pair: lo halfword = a, hi halfword = b
__device__ inline uint32_t pack_bf16_rne(float a, float b) {
    uint32_t ua = __builtin_bit_cast(uint32_t, a);
    uint32_t ub = __builtin_bit_cast(uint32_t, b);
    ua += 0x7fffu + ((ua >> 16) & 1u);
    ub += 0x7fffu + ((ub >> 16) & 1u);
    return (ua >> 16) | (ub & 0xffff0000u);
}

// Prep: one wave per row. Reads fp32 row (128 elems), writes bf16 row
// (64 u32, coalesced 256B) and the row sum-of-squares.
// rows [0, BATCH) -> x, rows [BATCH, BATCH+OUTF) -> w.
__global__ __launch_bounds__(256) void prep_kernel(
        const float* __restrict__ x, const float* __restrict__ w,
        float* __restrict__ sumsq, uint32_t* __restrict__ xb,
        uint32_t* __restrict__ wb) {
    int gtid = blockIdx.x * 256 + threadIdx.x;
    int row  = gtid >> 6;
    int lane = threadIdx.x & 63;
    if (row >= BATCH + OUTF) return;
    const float* src;
    uint32_t* dst;
    if (row < BATCH) {
        src = x + (size_t)row * INF;
        dst = xb + (size_t)row * 64;
    } else {
        src = w + (size_t)(row - BATCH) * INF;
        dst = wb + (size_t)(row - BATCH) * 64;
    }
    float2 v = *(const float2*)(src + lane * 2);
    dst[lane] = pack_bf16_rne(v.x, v.y);
    float s = v.x * v.x + v.y * v.y;
    #pragma unroll
    for (int off = 32; off; off >>= 1) s += __shfl_down(s, off);
    if (lane == 0) sumsq[row] = s;
}

#define TPAD 132  // LDS row stride (floats); 2-way bank aliasing only (free)

// 128x128 output tile per block, 4 waves (2x2), mfma 16x16x32 bf16.
// Epilogue via LDS transpose -> contiguous 512B/row float4 PLAIN stores
// (single-variable A/B vs R4: nontemporal removed).
__global__ __launch_bounds__(256, 2) void gemm_epi_kernel(
        const __bf16* __restrict__ xb, const __bf16* __restrict__ wb,
        const float* __restrict__ x2, const float* __restrict__ w2,
        float* __restrict__ out) {
    // bijective XCD-chunked swizzle: nwg = 4096 (divisible by 8).
    // Per XCD: nt sweeps fast -> 32KB x-panel L2-resident across 8 n-tiles.
    int bid = blockIdx.x;
    int swz = (bid & 7) * (4096 / 8) + (bid >> 3);
    int mt = swz >> 3;          // 512 m-tiles
    int nt = swz & 7;           // 8 n-tiles
    int m0 = mt * 128, n0 = nt * 128;

    int tid  = threadIdx.x;
    int wid  = tid >> 6;
    int lane = tid & 63;
    int wr = wid >> 1, wc = wid & 1;    // 2x2 wave grid, 64x64 per wave
    int row_base = m0 + wr * 64;
    int col_base = n0 + wc * 64;

    __shared__ float sx2[128];
    __shared__ float sw2[128];
    __shared__ float tile[128 * TPAD];
    if (tid < 128) {
        sx2[tid] = x2[m0 + tid];
        sw2[tid] = w2[n0 + tid];
    }
    __syncthreads();

    int l16 = lane & 15;   // row/col within fragment
    int lq  = lane >> 4;   // k-quarter selector

    f32x4 acc[4][4];
    #pragma unroll
    for (int i = 0; i < 4; ++i)
        #pragma unroll
        for (int j = 0; j < 4; ++j)
            acc[i][j] = f32x4{0.f, 0.f, 0.f, 0.f};

    #pragma unroll
    for (int ks = 0; ks < 4; ++ks) {
        int kbase = ks * 32 + lq * 8;
        bf16x8 a[4], b[4];
        #pragma unroll
        for (int im = 0; im < 4; ++im)
            a[im] = *(const bf16x8*)(xb + (size_t)(row_base + im * 16 + l16) * INF + kbase);
        #pragma unroll
        for (int in = 0; in < 4; ++in)
            b[in] = *(const bf16x8*)(wb + (size_t)(col_base + in * 16 + l16) * INF + kbase);
        #pragma unroll
        for (int im = 0; im < 4; ++im)
            #pragma unroll
            for (int in = 0; in < 4; ++in)
                acc[im][in] = __builtin_amdgcn_mfma_f32_16x16x32_bf16(
                    a[im], b[in], acc[im][in], 0, 0, 0);
    }

    // Phase 1: fused epilogue math into LDS tile.
    // C/D layout (verified m89/m91): col = lane&15, row = (lane>>4)*4 + reg
    #pragma unroll
    for (int im = 0; im < 4; ++im) {
        #pragma unroll
        for (int in = 0; in < 4; ++in) {
            #pragma unroll
            for (int r = 0; r < 4; ++r) {
                int row = wr * 64 + im * 16 + lq * 4 + r;  // within 128-tile
                int col = wc * 64 + in * 16 + l16;
                float d2 = sx2[row] + sw2[col] - 2.0f * acc[im][in][r];
                tile[row * TPAD + col] = -0.5f * __builtin_amdgcn_sqrtf(fmaxf(d2, 0.0f));
            }
        }
    }
    __syncthreads();

    // Phase 2: coalesced PLAIN float4 stores, 512B contiguous per row.
    int cg = tid & 31;           // col group (16B)
    int r8 = tid >> 5;           // 0..7
    #pragma unroll
    for (int chunk = 0; chunk < 16; ++chunk) {
        int row = chunk * 8 + r8;
        f32x4 v = *(const f32x4*)&tile[row * TPAD + cg * 4];
        *(f32x4*)&out[(size_t)(m0 + row) * OUTF + n0 + cg * 4] = v;
    }
}

extern "C" void kernel_launch(void* const* d_in, const int* in_sizes, int n_in,
                              void* d_out, int out_size, void* d_ws, size_t ws_size,
                              hipStream_t stream) {
    const float* x = (const float*)d_in[0];
    const float* w = (const float*)d_in[1];
    float* out = (float*)d_out;

    // ws layout: [0, 66560*4) f32 sumsq (x2 then w2);
    // xb (bf16 x, 16 MiB) at byte 266240 (256-aligned); wb after it.
    char* ws = (char*)d_ws;
    float* sumsq = (float*)ws;
    float* x2 = sumsq;
    float* w2 = sumsq + BATCH;
    uint32_t* xb_u32 = (uint32_t*)(ws + 266240);
    uint32_t* wb_u32 = (uint32_t*)(ws + 266240 + (size_t)BATCH * INF * 2);
    const __bf16* xb = (const __bf16*)xb_u32;
    const __bf16* wb = (const __bf16*)wb_u32;

    prep_kernel<<<dim3((BATCH + OUTF) / 4), dim3(256), 0, stream>>>(
        x, w, sumsq, xb_u32, wb_u32);
    gemm_epi_kernel<<<dim3(4096), dim3(256), 0, stream>>>(xb, wb, x2, w2, out);
}

// Round 9
// 95.562 us; speedup vs baseline: 1.3525x; 1.0403x over previous
//
#include <hip/hip_runtime.h>
#include <stdint.h>
#include <stddef.h>

#define BATCH 65536
#define OUTF  1024
#define INF   128

typedef float f32x4 __attribute__((ext_vector_type(4)));
typedef __bf16 bf16x8 __attribute__((ext_vector_type(8)));

#define CPAD 68   // LDS chunk-row stride (floats): 64 + 4 pad

// RNE float->bf16, packed pair
__device__ inline uint32_t pack_bf16_rne(float a, float b) {
    uint32_t ua = __builtin_bit_cast(uint32_t, a);
    uint32_t ub = __builtin_bit_cast(uint32_t, b);
    ua += 0x7fffu + ((ua >> 16) & 1u);
    ub += 0x7fffu + ((ub >> 16) & 1u);
    return (ua >> 16) | (ub & 0xffff0000u);
}

// Load 8 contiguous fp32, accumulate sum of squares, return bf16x8 fragment.
__device__ inline bf16x8 load_frag_x2(const float* __restrict__ p, float& s) {
    f32x4 v0 = *(const f32x4*)(p);
    f32x4 v1 = *(const f32x4*)(p + 4);
    s += v0.x * v0.x + v0.y * v0.y + v0.z * v0.z + v0.w * v0.w
       + v1.x * v1.x + v1.y * v1.y + v1.z * v1.z + v1.w * v1.w;
    union { uint32_t u[4]; bf16x8 b; } f;
    f.u[0] = pack_bf16_rne(v0.x, v0.y);
    f.u[1] = pack_bf16_rne(v0.z, v0.w);
    f.u[2] = pack_bf16_rne(v1.x, v1.y);
    f.u[3] = pack_bf16_rne(v1.z, v1.w);
    return f.b;
}

// W-only prep: one wave per w-row -> bf16 row + sumsq. 1024 rows, tiny.
__global__ __launch_bounds__(256) void wprep_kernel(
        const float* __restrict__ w, float* __restrict__ w2,
        uint32_t* __restrict__ wb) {
    int gtid = blockIdx.x * 256 + threadIdx.x;
    int row  = gtid >> 6;
    int lane = threadIdx.x & 63;
    if (row >= OUTF) return;
    const float* src = w + (size_t)row * INF;
    float2 v = *(const float2*)(src + lane * 2);
    wb[(size_t)row * 64 + lane] = pack_bf16_rne(v.x, v.y);
    float s = v.x * v.x + v.y * v.y;
    #pragma unroll
    for (int off = 32; off; off >>= 1) s += __shfl_down(s, off);
    if (lane == 0) w2[row] = s;
}

// Fused persistent-style GEMM+epilogue: 512 blocks (exactly 2/CU), each owns
// 128 x-rows x ALL 1024 cols, looping 16 col-chunks of 64. x fp32 converted
// to register A-frags ONCE per block (no prep bounce); x2 via shfl reduce.
// Per chunk: B from L2-resident W, 32 MFMA/wave, epilogue -> dbuf LDS ->
// NT f32x4 stores. Stores issue in 16 spread bursts -> continuous write flow.
__global__ __launch_bounds__(256, 2) void fused_kernel(
        const float* __restrict__ x, const __bf16* __restrict__ wb,
        const float* __restrict__ w2, float* __restrict__ out) {
    int tid  = threadIdx.x;
    int wid  = tid >> 6;
    int lane = tid & 63;
    int l16  = lane & 15;   // fragment row/col
    int lq   = lane >> 4;   // k-quarter (loads) / row-quad (epilogue)

    int row_base = blockIdx.x * 128 + wid * 32;   // this wave's 32 rows

    __shared__ float sw2[OUTF];
    __shared__ float tile2[2][128 * CPAD];
    #pragma unroll
    for (int j = 0; j < 4; ++j)
        sw2[tid + 256 * j] = w2[tid + 256 * j];

    // A fragments (2 im x 4 ks, 32 VGPR) + per-row sumsq partials, loaded once.
    bf16x8 a[4][2];
    float x2p[2] = {0.f, 0.f};
    #pragma unroll
    for (int ks = 0; ks < 4; ++ks)
        #pragma unroll
        for (int im = 0; im < 2; ++im)
            a[ks][im] = load_frag_x2(
                &x[(size_t)(row_base + im * 16 + l16) * INF + ks * 32 + lq * 8],
                x2p[im]);

    // Row sumsq: butterfly over k-quarter groups; lanes l16,l16+16,.. same val.
    #pragma unroll
    for (int im = 0; im < 2; ++im) {
        float s = x2p[im];
        s += __shfl_xor(s, 16);
        s += __shfl_xor(s, 32);
        x2p[im] = s;
    }
    // Epilogue layout redistribute: lane (lq,l16) needs rows lq*4+r.
    float x2row[2][4];
    #pragma unroll
    for (int im = 0; im < 2; ++im)
        #pragma unroll
        for (int r = 0; r < 4; ++r)
            x2row[im][r] = __shfl(x2p[im], lq * 20 + r);

    __syncthreads();   // sw2 ready

    int srow = tid >> 4;     // store row base 0..15
    int scg  = tid & 15;     // store col group (16B)

    for (int nc = 0; nc < 16; ++nc) {
        int n0 = nc * 64;
        float* buf = tile2[nc & 1];

        f32x4 acc[2][4];
        #pragma unroll
        for (int im = 0; im < 2; ++im)
            #pragma unroll
            for (int in = 0; in < 4; ++in)
                acc[im][in] = f32x4{0.f, 0.f, 0.f, 0.f};

        #pragma unroll
        for (int ks = 0; ks < 4; ++ks) {
            bf16x8 b[4];
            #pragma unroll
            for (int in = 0; in < 4; ++in)
                b[in] = *(const bf16x8*)(
                    wb + (size_t)(n0 + in * 16 + l16) * INF + ks * 32 + lq * 8);
            #pragma unroll
            for (int im = 0; im < 2; ++im)
                #pragma unroll
                for (int in = 0; in < 4; ++in)
                    acc[im][in] = __builtin_amdgcn_mfma_f32_16x16x32_bf16(
                        a[ks][im], b[in], acc[im][in], 0, 0, 0);
        }

        // Epilogue math into LDS chunk (C/D layout: col=l16, row=lq*4+r).
        #pragma unroll
        for (int im = 0; im < 2; ++im) {
            #pragma unroll
            for (int in = 0; in < 4; ++in) {
                #pragma unroll
                for (int r = 0; r < 4; ++r) {
                    int rloc = wid * 32 + im * 16 + lq * 4 + r;   // 0..127
                    int col  = in * 16 + l16;
                    float d2 = x2row[im][r] + sw2[n0 + col] - 2.0f * acc[im][in][r];
                    buf[rloc * CPAD + col] =
                        -0.5f * __builtin_amdgcn_sqrtf(fmaxf(d2, 0.0f));
                }
            }
        }
        __syncthreads();
        // Dbuf alternation + this barrier orders reuse (reads of buf finish
        // before the epilogue two chunks later rewrites it).

        // Store chunk: 128 rows x 256B contiguous segments, NT f32x4.
        #pragma unroll
        for (int k = 0; k < 8; ++k) {
            int row = srow + k * 16;
            f32x4 v = *(const f32x4*)&buf[row * CPAD + scg * 4];
            __builtin_nontemporal_store(
                v, (f32x4*)&out[(size_t)(blockIdx.x * 128 + row) * OUTF + n0 + scg * 4]);
        }
    }
}

extern "C" void kernel_launch(void* const* d_in, const int* in_sizes, int n_in,
                              void* d_out, int out_size, void* d_ws, size_t ws_size,
                              hipStream_t stream) {
    const float* x = (const float*)d_in[0];
    const float* w = (const float*)d_in[1];
    float* out = (float*)d_out;

    // ws layout: w2 [1024 f32] at 0; wb (bf16 W, 256KB) at byte 4096.
    char* ws = (char*)d_ws;
    float* w2 = (float*)ws;
    uint32_t* wb_u32 = (uint32_t*)(ws + 4096);
    const __bf16* wb = (const __bf16*)wb_u32;

    wprep_kernel<<<dim3(OUTF / 4), dim3(256), 0, stream>>>(w, w2, wb_u32);
    fused_kernel<<<dim3(BATCH / 128), dim3(256), 0, stream>>>(x, wb, w2, out);
}

// Round 10
// 92.051 us; speedup vs baseline: 1.4041x; 1.0381x over previous
//
#include <hip/hip_runtime.h>
#include <stdint.h>
#include <stddef.h>

#define BATCH 65536
#define OUTF  1024
#define INF   128

typedef float f32x4 __attribute__((ext_vector_type(4)));
typedef __bf16 bf16x8 __attribute__((ext_vector_type(8)));

#define CPAD 68   // wave-scratch row stride (floats): 64 + 4

// RNE float->bf16, packed pair
__device__ inline uint32_t pack_bf16_rne(float a, float b) {
    uint32_t ua = __builtin_bit_cast(uint32_t, a);
    uint32_t ub = __builtin_bit_cast(uint32_t, b);
    ua += 0x7fffu + ((ua >> 16) & 1u);
    ub += 0x7fffu + ((ub >> 16) & 1u);
    return (ua >> 16) | (ub & 0xffff0000u);
}

// Load 8 contiguous fp32, accumulate sum of squares, return bf16x8 fragment.
__device__ inline bf16x8 load_frag_x2(const float* __restrict__ p, float& s) {
    f32x4 v0 = *(const f32x4*)(p);
    f32x4 v1 = *(const f32x4*)(p + 4);
    s += v0.x * v0.x + v0.y * v0.y + v0.z * v0.z + v0.w * v0.w
       + v1.x * v1.x + v1.y * v1.y + v1.z * v1.z + v1.w * v1.w;
    union { uint32_t u[4]; bf16x8 b; } f;
    f.u[0] = pack_bf16_rne(v0.x, v0.y);
    f.u[1] = pack_bf16_rne(v0.z, v0.w);
    f.u[2] = pack_bf16_rne(v1.x, v1.y);
    f.u[3] = pack_bf16_rne(v1.z, v1.w);
    return f.b;
}

// W-only prep: one wave per w-row -> bf16 row + sumsq. 1024 rows, tiny.
__global__ __launch_bounds__(256) void wprep_kernel(
        const float* __restrict__ w, float* __restrict__ w2,
        uint32_t* __restrict__ wb) {
    int gtid = blockIdx.x * 256 + threadIdx.x;
    int row  = gtid >> 6;
    int lane = threadIdx.x & 63;
    if (row >= OUTF) return;
    const float* src = w + (size_t)row * INF;
    float2 v = *(const float2*)(src + lane * 2);
    wb[(size_t)row * 64 + lane] = pack_bf16_rne(v.x, v.y);
    float s = v.x * v.x + v.y * v.y;
    #pragma unroll
    for (int off = 32; off; off >>= 1) s += __shfl_down(s, off);
    if (lane == 0) w2[row] = s;
}

// Barrier-free fused GEMM+epilogue. 512 blocks (2/CU), each owns 128 x-rows
// x all 1024 cols in 16 chunks of 64. ONE __syncthreads total (sw2 staging,
// before any stores). Per-chunk transpose uses WAVE-PRIVATE LDS scratch
// (intra-wave ds ordering via lgkmcnt, no barrier), double-buffered.
// NT stores are issued and never explicitly waited -> vmcnt drains
// asynchronously under subsequent chunks' compute.
__global__ __launch_bounds__(256, 2) void fused_kernel(
        const float* __restrict__ x, const __bf16* __restrict__ wb,
        const float* __restrict__ w2, float* __restrict__ out) {
    int tid  = threadIdx.x;
    int wid  = tid >> 6;
    int lane = tid & 63;
    int l16  = lane & 15;   // fragment row/col
    int lq   = lane >> 4;   // k-quarter (loads) / row-quad (epilogue)

    int row_base = blockIdx.x * 128 + wid * 32;   // this wave's 32 rows

    __shared__ float sw2[OUTF];
    __shared__ float scratch[2][4][32 * CPAD];    // [dbuf][wave][row][col]
    #pragma unroll
    for (int j = 0; j < 4; ++j)
        sw2[tid + 256 * j] = w2[tid + 256 * j];

    // A fragments (2 im x 4 ks, 32 VGPR) + per-row sumsq partials, loaded once.
    bf16x8 a[4][2];
    float x2p[2] = {0.f, 0.f};
    #pragma unroll
    for (int ks = 0; ks < 4; ++ks)
        #pragma unroll
        for (int im = 0; im < 2; ++im)
            a[ks][im] = load_frag_x2(
                &x[(size_t)(row_base + im * 16 + l16) * INF + ks * 32 + lq * 8],
                x2p[im]);

    // Row sumsq: butterfly over k-quarter groups.
    #pragma unroll
    for (int im = 0; im < 2; ++im) {
        float s = x2p[im];
        s += __shfl_xor(s, 16);
        s += __shfl_xor(s, 32);
        x2p[im] = s;
    }
    // Epilogue layout redistribute: lane (lq,l16) needs rows lq*4+r.
    float x2row[2][4];
    #pragma unroll
    for (int im = 0; im < 2; ++im)
        #pragma unroll
        for (int r = 0; r < 4; ++r)
            x2row[im][r] = __shfl(x2p[im], lq * 20 + r);

    __syncthreads();   // sw2 ready — the ONLY barrier in this kernel

    for (int nc = 0; nc < 16; ++nc) {
        int n0 = nc * 64;
        float* buf = scratch[nc & 1][wid];

        f32x4 acc[2][4];
        #pragma unroll
        for (int im = 0; im < 2; ++im)
            #pragma unroll
            for (int in = 0; in < 4; ++in)
                acc[im][in] = f32x4{0.f, 0.f, 0.f, 0.f};

        #pragma unroll
        for (int ks = 0; ks < 4; ++ks) {
            bf16x8 b[4];
            #pragma unroll
            for (int in = 0; in < 4; ++in)
                b[in] = *(const bf16x8*)(
                    wb + (size_t)(n0 + in * 16 + l16) * INF + ks * 32 + lq * 8);
            #pragma unroll
            for (int im = 0; im < 2; ++im)
                #pragma unroll
                for (int in = 0; in < 4; ++in)
                    acc[im][in] = __builtin_amdgcn_mfma_f32_16x16x32_bf16(
                        a[ks][im], b[in], acc[im][in], 0, 0, 0);
        }

        // Epilogue math into this wave's private scratch.
        // C/D layout: col = l16, row = lq*4 + r (within each 16x16 fragment).
        #pragma unroll
        for (int im = 0; im < 2; ++im) {
            #pragma unroll
            for (int in = 0; in < 4; ++in) {
                #pragma unroll
                for (int r = 0; r < 4; ++r) {
                    int rloc = im * 16 + lq * 4 + r;              // 0..31
                    int col  = in * 16 + l16;
                    float d2 = x2row[im][r] + sw2[n0 + col] - 2.0f * acc[im][in][r];
                    buf[rloc * CPAD + col] =
                        -0.5f * __builtin_amdgcn_sqrtf(fmaxf(d2, 0.0f));
                }
            }
        }
        // Intra-wave ds_write -> ds_read ordering via lgkmcnt (compiler
        // emits the wait); no block barrier.

        // Store this wave's 32 rows x 64 cols: NT f32x4, 256B/row segments.
        #pragma unroll
        for (int k = 0; k < 8; ++k) {
            int row = k * 4 + (lane >> 4);
            f32x4 v = *(const f32x4*)&buf[row * CPAD + l16 * 4];
            __builtin_nontemporal_store(
                v, (f32x4*)&out[(size_t)(row_base + row) * OUTF + n0 + l16 * 4]);
        }
    }
}

extern "C" void kernel_launch(void* const* d_in, const int* in_sizes, int n_in,
                              void* d_out, int out_size, void* d_ws, size_t ws_size,
                              hipStream_t stream) {
    const float* x = (const float*)d_in[0];
    const float* w = (const float*)d_in[1];
    float* out = (float*)d_out;

    // ws layout: w2 [1024 f32] at 0; wb (bf16 W, 256KB) at byte 4096.
    char* ws = (char*)d_ws;
    float* w2 = (float*)ws;
    uint32_t* wb_u32 = (uint32_t*)(ws + 4096);
    const __bf16* wb = (const __bf16*)wb_u32;

    wprep_kernel<<<dim3(OUTF / 4), dim3(256), 0, stream>>>(w, w2, wb_u32);
    fused_kernel<<<dim3(BATCH / 128), dim3(256), 0, stream>>>(x, wb, w2, out);
}